// Round 4
// baseline (527.019 us; speedup 1.0000x reference)
//
#include <hip/hip_runtime.h>
#include <cstdint>
#include <cstddef>

// B=32, S=1024, H=768, L=28, NH=8, HD=96.  d_out = [loss(1), logits(896)] f32.

using short8 = __attribute__((ext_vector_type(8))) short;   // 8 bf16 = 16B
using f32x4  = __attribute__((ext_vector_type(4))) float;

__device__ __forceinline__ short f2bf(float f) {   // f32 -> bf16 RNE
  unsigned u = __builtin_bit_cast(unsigned, f);
  u = (u + 0x7fffu + ((u >> 16) & 1u)) >> 16;
  return (short)u;
}
__device__ __forceinline__ float bf2f(short s) {
  return __builtin_bit_cast(float, ((unsigned)(unsigned short)s) << 16);
}

#define MFMA16(a, b, c) __builtin_amdgcn_mfma_f32_16x16x32_bf16((a), (b), (c), 0, 0, 0)

__device__ __forceinline__ void gld16(const void* g, void* l) {
  __builtin_amdgcn_global_load_lds((const __attribute__((address_space(1))) void*)g,
                                   (__attribute__((address_space(3))) void*)l, 16, 0, 0);
}

// ---------------------------------------------------------------------------
__global__ __launch_bounds__(256) void cvt_k(const float* __restrict__ in, short* __restrict__ out) {
  size_t i = ((size_t)blockIdx.x * 256 + threadIdx.x) * 8;
  float4 a = *(const float4*)(in + i);
  float4 b = *(const float4*)(in + i + 4);
  short8 w;
  w[0]=f2bf(a.x); w[1]=f2bf(a.y); w[2]=f2bf(a.z); w[3]=f2bf(a.w);
  w[4]=f2bf(b.x); w[5]=f2bf(b.y); w[6]=f2bf(b.z); w[7]=f2bf(b.w);
  *(short8*)(out + i) = w;
}

// ---------------------------------------------------------------------------
// merged weight transpose+convert: 6 matrices in one launch. grid (24,24,6).
struct TcvtArgs { const float* src[6]; short* dst[6]; int Kd[6]; int Nd[6]; };

__global__ __launch_bounds__(256) void tcvt_all_k(TcvtArgs a) {
  const int z = blockIdx.z;
  const int K = a.Kd[z], N = a.Nd[z];
  if ((int)blockIdx.x * 64 >= N || (int)blockIdx.y * 64 >= K) return;  // block-uniform
  const float* __restrict__ in = a.src[z];
  short* __restrict__ out = a.dst[z];
  __shared__ float t[64][65];
  const int tid = threadIdx.x;
  const int bx = blockIdx.x, by = blockIdx.y;
  const int cr = tid >> 4, cc = (tid & 15) * 4;
#pragma unroll
  for (int p = 0; p < 4; p++) {
    int k = by * 64 + p * 16 + cr;
    float4 v = *(const float4*)(in + (size_t)k * N + bx * 64 + cc);
    t[p*16+cr][cc]   = v.x; t[p*16+cr][cc+1] = v.y;
    t[p*16+cr][cc+2] = v.z; t[p*16+cr][cc+3] = v.w;
  }
  __syncthreads();
  const int nl = tid >> 2, kl0 = (tid & 3) * 16;
  short8 w0, w1;
#pragma unroll
  for (int j = 0; j < 8; j++) w0[j] = f2bf(t[kl0 + j][nl]);
#pragma unroll
  for (int j = 0; j < 8; j++) w1[j] = f2bf(t[kl0 + 8 + j][nl]);
  short* op = out + (size_t)(bx * 64 + nl) * K + by * 64 + kl0;
  *(short8*)op       = w0;
  *(short8*)(op + 8) = w1;
}

// ---------------------------------------------------------------------------
__global__ __launch_bounds__(256) void pool_k(const float* __restrict__ hidden, const int* __restrict__ lp,
                                              float* __restrict__ outf, short* __restrict__ outb) {
  const int blk = blockIdx.x;            // b*28 + l
  const int b = blk / 28;
  const int start = lp[blk * 2], len = lp[blk * 2 + 1];
  const float inv = 1.f / (float)max(len, 1);
#pragma unroll
  for (int j = 0; j < 3; j++) {
    int h = threadIdx.x + j * 256;
    float s = 0.f;
    for (int q = 0; q < len; q++)
      s += hidden[((size_t)b * 1024 + start + q) * 768 + h];
    float m = s * inv;
    outf[(size_t)blk * 768 + h] = m;
    outb[(size_t)blk * 768 + h] = f2bf(m);
  }
}

// ---------------------------------------------------------------------------
// 128x128 MFMA GEMM, 2-phase double-buffered pipeline (counted vmcnt, raw s_barrier).
// A [M,K] bf16 rm, Bt [N,K] bf16 rm. 4 waves (2x2), 4x4 frags of 16x16x32 each.
// LDS: 2 bufs x (A 8KB + B 8KB), XOR swizzle bits4-5 ^= bits7-8 (0 bank conflicts, r1-measured).
// MODE 0: bf16 out    MODE 1: KV scatter (k[b,n,s,d], vT[b,n,d,s])
// MODE 2: f32 out     MODE 3: bf16 gelu out
template <int MODE>
__global__ __launch_bounds__(256) void gemm_k(
    const short* __restrict__ A, const short* __restrict__ Bt,
    const float* __restrict__ bias, const float* __restrict__ bias2,
    float* __restrict__ outf, short* __restrict__ outb, short* __restrict__ outb2,
    int K, int N) {
  __shared__ __align__(16) char lds[32768];
  const int tid = threadIdx.x, lane = tid & 63, wid = tid >> 6;
  const int wm = wid >> 1, wn = wid & 1;
  const int m0 = blockIdx.x * 128, n0 = blockIdx.y * 128;
  const int lr = lane & 15, lg = lane >> 4;

  int aoff = (wm * 64 + lr) * 64 + lg * 16;
  aoff ^= ((aoff >> 7) & 3) << 4;
  int boff = (wn * 64 + lr) * 64 + lg * 16;
  boff ^= ((boff >> 7) & 3) << 4;
  boff += 8192;

  // staging: LDS linear dest d -> logical o = swz(d) -> global (row, col)
  const int d0 = wid * 1024 + lane * 16;
  const int d1 = d0 + 4096;
  const int o0 = d0 ^ (((d0 >> 7) & 3) << 4);
  const int o1 = d1 ^ (((d1 >> 7) & 3) << 4);
  const int r0 = o0 >> 6, c0 = (o0 & 63) >> 1;
  const int r1 = o1 >> 6, c1 = (o1 & 63) >> 1;
  const short* pA0 = A + (size_t)(m0 + r0) * K + c0;
  const short* pA1 = A + (size_t)(m0 + r1) * K + c1;
  const short* pB0 = Bt + (size_t)(n0 + r0) * K + c0;
  const short* pB1 = Bt + (size_t)(n0 + r1) * K + c1;

  f32x4 acc[4][4];
  const f32x4 zf = {0.f, 0.f, 0.f, 0.f};
#pragma unroll
  for (int i = 0; i < 4; i++)
#pragma unroll
    for (int j = 0; j < 4; j++) acc[i][j] = zf;

  auto STAGE = [&](int buf, int kk) {
    char* db = lds + buf * 16384;
    gld16(pA0 + kk, db + wid * 1024);
    gld16(pA1 + kk, db + 4096 + wid * 1024);
    gld16(pB0 + kk, db + 8192 + wid * 1024);
    gld16(pB1 + kk, db + 12288 + wid * 1024);
  };

  STAGE(0, 0);                                   // prologue: 4 loads in flight
  int cur = 0;
  for (int k0 = 0; k0 < K; k0 += 32) {
    __builtin_amdgcn_sched_barrier(0);           // keep STAGE below prev iter's barrier
    const int kn = (k0 + 32 < K) ? (k0 + 32) : 0;  // last iter: harmless reload of tile 0
    STAGE(cur ^ 1, kn);                          // outstanding: 4 (cur) + 4 (next)
    asm volatile("s_waitcnt vmcnt(4)" ::: "memory");  // wait own cur-tile loads only
    __builtin_amdgcn_s_barrier();                // raw barrier: no vmcnt(0) drain
    __builtin_amdgcn_sched_barrier(0);           // no ds_read hoisted above barrier
    const char* bb_ = lds + cur * 16384;
    short8 af[4], bq8[4];
#pragma unroll
    for (int i = 0; i < 4; i++) af[i] = *(const short8*)(bb_ + aoff + i * 1024);
#pragma unroll
    for (int j = 0; j < 4; j++) bq8[j] = *(const short8*)(bb_ + boff + j * 1024);
#pragma unroll
    for (int i = 0; i < 4; i++)
#pragma unroll
      for (int j = 0; j < 4; j++)
        acc[i][j] = MFMA16(af[i], bq8[j], acc[i][j]);
    __builtin_amdgcn_sched_barrier(0);
    __builtin_amdgcn_s_barrier();                // all reads of buf[cur] done
    cur ^= 1;
  }

  if constexpr (MODE == 1) {
    const int b = m0 >> 10;
    const int sb = (m0 & 1023) + wm * 64;
#pragma unroll
    for (int j = 0; j < 4; j++) {
      int c = n0 + wn * 64 + j * 16 + lr;
      bool isv = c >= 768;                       // uniform per wave
      int c7 = isv ? c - 768 : c;
      int nh = c7 / 96;
      int dd = c7 - nh * 96;
      float bb = isv ? bias2[c7] : bias[c7];
      size_t base = isv ? ((size_t)((b * 8 + nh) * 96 + dd)) * 1024
                        : (size_t)(b * 8 + nh) * 98304 + dd;
      short* op = isv ? outb2 : outb;
#pragma unroll
      for (int i = 0; i < 4; i++) {
        int s0 = sb + i * 16 + lg * 4;
#pragma unroll
        for (int t = 0; t < 4; t++) {
          short v = f2bf(acc[i][j][t] + bb);
          if (isv) op[base + s0 + t] = v;                 // vT[b,n,d,s] (8B merged)
          else     op[base + (size_t)(s0 + t) * 96] = v;  // k[b,n,s,d]
        }
      }
    }
  } else {
    const int rb = m0 + wm * 64;
    const int cb = n0 + wn * 64;
#pragma unroll
    for (int j = 0; j < 4; j++) {
      int c = cb + j * 16 + lr;
      float bb = bias[c];
#pragma unroll
      for (int i = 0; i < 4; i++) {
        int r = rb + i * 16 + lg * 4;
#pragma unroll
        for (int t = 0; t < 4; t++) {
          float v = acc[i][j][t] + bb;
          if constexpr (MODE == 0) {
            outb[(size_t)(r + t) * N + c] = f2bf(v);
          } else if constexpr (MODE == 2) {
            outf[(size_t)(r + t) * N + c] = v;
          } else {
            float ge = v * 0.5f * (1.f + erff(v * 0.70710678118654752f));
            outb[(size_t)(r + t) * N + c] = f2bf(ge);
          }
        }
      }
    }
  }
}

// ---------------------------------------------------------------------------
// cross-attention, one block per (b,head). Scores in LDS as bf16 [32][1040]
// (66.5 KB -> 2 blocks/CU). Phase-3 P fragments are direct short8 LDS reads.
#define SROWS 1040
__global__ __launch_bounds__(256, 2) void attn_k(
    const short* __restrict__ qb, const short* __restrict__ kb,
    const short* __restrict__ vtb, short* __restrict__ ctxb) {
  __shared__ __align__(16) short sc[32 * SROWS];     // 66560 B
  __shared__ float rowsum[28];
  const int b = blockIdx.x >> 3, n = blockIdx.x & 7;
  const int tid = threadIdx.x, lane = tid & 63, wid = tid >> 6;
  const int lr = lane & 15, lg = lane >> 4;
  const float rs = 0.10206207261596575f;             // 1/sqrt(96)
  const f32x4 zf = {0.f, 0.f, 0.f, 0.f};
  const short8 z8 = {0, 0, 0, 0, 0, 0, 0, 0};

  short8 aq[2][3];                                   // Q fragments, rows >= 28 zero
#pragma unroll
  for (int mt = 0; mt < 2; mt++) {
    int row = mt * 16 + lr;
#pragma unroll
    for (int kk = 0; kk < 3; kk++)
      aq[mt][kk] = (row < 28)
          ? *(const short8*)(qb + (size_t)(b * 28 + row) * 768 + n * 96 + kk * 32 + lg * 8)
          : z8;
  }

  // phase 1: scores -> bf16 LDS. wave w owns s in [w*256, w*256+256)
  const short* kbase = kb + (size_t)(b * 8 + n) * 98304;
#pragma unroll 2
  for (int st = 0; st < 16; st++) {
    int s0 = wid * 256 + st * 16;
    f32x4 a0 = zf, a1 = zf;
#pragma unroll
    for (int kk = 0; kk < 3; kk++) {
      short8 bk8 = *(const short8*)(kbase + (size_t)(s0 + lr) * 96 + kk * 32 + lg * 8);
      a0 = MFMA16(aq[0][kk], bk8, a0);
      a1 = MFMA16(aq[1][kk], bk8, a1);
    }
#pragma unroll
    for (int t = 0; t < 4; t++) {
      sc[(lg * 4 + t) * SROWS + s0 + lr]      = f2bf(a0[t] * rs);
      sc[(16 + lg * 4 + t) * SROWS + s0 + lr] = f2bf(a1[t] * rs);
    }
  }
  __syncthreads();

  // phase 2: softmax rows (unnormalized exp, bf16 writeback). wave w rows [7w,7w+7)
  for (int rr = 0; rr < 7; rr++) {
    int r = wid * 7 + rr;
    short* rp = sc + r * SROWS;
    float v[16];
    float mx = -3.0e38f;
#pragma unroll
    for (int t = 0; t < 16; t++) { v[t] = bf2f(rp[lane + t * 64]); mx = fmaxf(mx, v[t]); }
#pragma unroll
    for (int o = 32; o > 0; o >>= 1) mx = fmaxf(mx, __shfl_xor(mx, o));
    float sm = 0.f;
#pragma unroll
    for (int t = 0; t < 16; t++) { v[t] = __expf(v[t] - mx); sm += v[t]; }
#pragma unroll
    for (int o = 32; o > 0; o >>= 1) sm += __shfl_xor(sm, o);
#pragma unroll
    for (int t = 0; t < 16; t++) rp[lane + t * 64] = f2bf(v[t]);
    if (lane == 0) rowsum[r] = sm;
  }
  // rows 28..31 hold raw score 0 (zeroed Q rows) == P 0: no explicit zeroing needed
  __syncthreads();

  // phase 3: ctx partial = P @ V over this wave's s-range
  f32x4 acc2[2][6];
#pragma unroll
  for (int mt = 0; mt < 2; mt++)
#pragma unroll
    for (int nt = 0; nt < 6; nt++) acc2[mt][nt] = zf;
  const short* vbase = vtb + (size_t)(b * 8 + n) * 98304;
#pragma unroll 2
  for (int ks = 0; ks < 8; ks++) {
    int s0 = wid * 256 + ks * 32;
    short8 pa0 = *(const short8*)(sc + (size_t)lr * SROWS + s0 + lg * 8);
    short8 pa1 = *(const short8*)(sc + (size_t)(16 + lr) * SROWS + s0 + lg * 8);
#pragma unroll
    for (int nt = 0; nt < 6; nt++) {
      short8 bv8 = *(const short8*)(vbase + (size_t)(nt * 16 + lr) * 1024 + s0 + lg * 8);
      acc2[0][nt] = MFMA16(pa0, bv8, acc2[0][nt]);
      acc2[1][nt] = MFMA16(pa1, bv8, acc2[1][nt]);
    }
  }
  __syncthreads();                                   // sc reads done; reuse as f32 partials
  float* part = (float*)sc;                          // [4][32][96] = 49152 B
#pragma unroll
  for (int mt = 0; mt < 2; mt++)
#pragma unroll
    for (int nt = 0; nt < 6; nt++)
#pragma unroll
      for (int t = 0; t < 4; t++)
        part[wid * 3072 + (mt * 16 + lg * 4 + t) * 96 + nt * 16 + lr] = acc2[mt][nt][t];
  __syncthreads();
  for (int idx = tid; idx < 2688; idx += 256) {
    int l = idx / 96, d = idx - (idx / 96) * 96;
    float s = part[idx] + part[3072 + idx] + part[6144 + idx] + part[9216 + idx];
    ctxb[(size_t)(b * 28 + l) * 768 + n * 96 + d] = f2bf(s / rowsum[l]);
  }
}

// ---------------------------------------------------------------------------
__device__ __forceinline__ float blk_sum4(float v, float* red) {
  const int lane = threadIdx.x & 63, wid = threadIdx.x >> 6;
#pragma unroll
  for (int o = 32; o > 0; o >>= 1) v += __shfl_xor(v, o);
  __syncthreads();
  if (lane == 0) red[wid] = v;
  __syncthreads();
  return red[0] + red[1] + red[2] + red[3];
}

__global__ __launch_bounds__(256) void ln1_k(const float* __restrict__ ao, const float* __restrict__ lh,
                                             const float* __restrict__ g, const float* __restrict__ bb,
                                             float* __restrict__ x1, short* __restrict__ x1b) {
  __shared__ float red[4];
  const int row = blockIdx.x, tid = threadIdx.x;
  const size_t base = (size_t)row * 768;
  float x[3], s1 = 0.f, s2 = 0.f;
#pragma unroll
  for (int j = 0; j < 3; j++) {
    int c = tid + j * 256;
    x[j] = ao[base + c] + lh[base + c];
    s1 += x[j]; s2 += x[j] * x[j];
  }
  s1 = blk_sum4(s1, red);
  s2 = blk_sum4(s2, red);
  float mu = s1 * (1.f / 768.f);
  float inv = rsqrtf(s2 * (1.f / 768.f) - mu * mu + 1e-5f);
#pragma unroll
  for (int j = 0; j < 3; j++) {
    int c = tid + j * 256;
    float y = (x[j] - mu) * inv * g[c] + bb[c];
    x1[base + c] = y;
    x1b[base + c] = f2bf(y);
  }
}

__global__ __launch_bounds__(256) void ln2_k(const float* __restrict__ z, const float* __restrict__ x1,
                                             const float* __restrict__ g, const float* __restrict__ bb,
                                             const float* __restrict__ wc, const float* __restrict__ bc,
                                             float* __restrict__ dout) {
  __shared__ float red[4];
  const int row = blockIdx.x, tid = threadIdx.x;
  const size_t base = (size_t)row * 768;
  float x[3], s1 = 0.f, s2 = 0.f;
#pragma unroll
  for (int j = 0; j < 3; j++) {
    int c = tid + j * 256;
    x[j] = z[base + c] + x1[base + c];
    s1 += x[j]; s2 += x[j] * x[j];
  }
  s1 = blk_sum4(s1, red);
  s2 = blk_sum4(s2, red);
  float mu = s1 * (1.f / 768.f);
  float inv = rsqrtf(s2 * (1.f / 768.f) - mu * mu + 1e-5f);
  float dacc = 0.f;
#pragma unroll
  for (int j = 0; j < 3; j++) {
    int c = tid + j * 256;
    float y = (x[j] - mu) * inv * g[c] + bb[c];
    dacc += y * wc[c];
  }
  dacc = blk_sum4(dacc, red);
  if (tid == 0) dout[1 + row] = dacc + bc[0];
}

// merged pair-loss + bce + final loss: one block, 1024 threads.
__global__ __launch_bounds__(1024) void corrloss_k(const float* __restrict__ labels,
                                                   float* __restrict__ dout) {
  __shared__ float lg[896], lb[896];
  __shared__ float red[64];
  const int tid = threadIdx.x;
  if (tid < 896) { lg[tid] = dout[1 + tid]; lb[tid] = labels[tid]; }
  __syncthreads();
  float bce = 0.f, pos = 0.f, neg = 0.f;
  if (tid < 896) {
    float l = lg[tid], y = lb[tid];
    bce = fmaxf(l, 0.f) - l * y + log1pf(expf(-fabsf(l)));
    pos = y; neg = 1.f - y;
  }
  float a = 0.f;
  const int isub = tid >> 5, jsub = tid & 31;
  for (int ib = 0; ib < 28; ib++) {
    int i = ib * 32 + isub;
    if (lb[i] == 1.f) {
      float li = lg[i];
#pragma unroll 4
      for (int jb = 0; jb < 28; jb++) {
        int j = jsub + jb * 32;
        if (lb[j] == 0.f) a += fmaxf(lg[j] - li + 0.3f, 0.f);
      }
    }
  }
#pragma unroll
  for (int o = 32; o > 0; o >>= 1) {
    bce += __shfl_xor(bce, o); pos += __shfl_xor(pos, o);
    neg += __shfl_xor(neg, o); a   += __shfl_xor(a, o);
  }
  const int w = tid >> 6;
  if ((tid & 63) == 0) { red[w] = bce; red[16 + w] = pos; red[32 + w] = neg; red[48 + w] = a; }
  __syncthreads();
  if (tid == 0) {
    float sb = 0.f, sp = 0.f, sn = 0.f, sa = 0.f;
#pragma unroll
    for (int k = 0; k < 16; k++) { sb += red[k]; sp += red[16 + k]; sn += red[32 + k]; sa += red[48 + k]; }
    float denom = sp * sn;
    float corr = denom > 0.f ? sa / fmaxf(denom, 1.f) : 0.f;
    dout[0] = 0.8f * sb * (1.f / 896.f) + 0.2f * corr;
  }
}

// ---------------------------------------------------------------------------
extern "C" void kernel_launch(void* const* d_in, const int* in_sizes, int n_in,
                              void* d_out, int out_size, void* d_ws, size_t ws_size,
                              hipStream_t stream) {
  const float* hidden = (const float*)d_in[0];
  const float* labels = (const float*)d_in[1];
  const int*   lpos   = (const int*)d_in[2];
  const float* Wq = (const float*)d_in[3];  const float* bq = (const float*)d_in[4];
  const float* Wk = (const float*)d_in[5];  const float* bk = (const float*)d_in[6];
  const float* Wv = (const float*)d_in[7];  const float* bv = (const float*)d_in[8];
  const float* Wo = (const float*)d_in[9];  const float* bo = (const float*)d_in[10];
  const float* g_mha = (const float*)d_in[11]; const float* b_mha = (const float*)d_in[12];
  const float* W1 = (const float*)d_in[13]; const float* bf1 = (const float*)d_in[14];
  const float* W2 = (const float*)d_in[15]; const float* bf2 = (const float*)d_in[16];
  const float* g_ffn = (const float*)d_in[17]; const float* b_ffn = (const float*)d_in[18];
  const float* wc = (const float*)d_in[19]; const float* bc = (const float*)d_in[20];
  float* dout = (float*)d_out;

  char* ws = (char*)d_ws;
  size_t off = 0;
  auto alloc = [&](size_t bytes) { char* p = ws + off; off += (bytes + 255) & ~(size_t)255; return p; };
  short* hid_b = (short*)alloc(32ull * 1024 * 768 * 2);
  short* WqT   = (short*)alloc(768ull * 768 * 2);
  short* WkvT  = (short*)alloc(1536ull * 768 * 2);
  short* WoT   = (short*)alloc(768ull * 768 * 2);
  short* W1T   = (short*)alloc(1536ull * 768 * 2);
  short* W2T   = (short*)alloc(768ull * 1536 * 2);
  float* poolf = (float*)alloc(896ull * 768 * 4);
  short* poolb = (short*)alloc(896ull * 768 * 2);
  short* qbf   = (short*)alloc(896ull * 768 * 2);
  short* kbf   = (short*)alloc(32ull * 8 * 1024 * 96 * 2);
  short* vtb   = (short*)alloc(32ull * 8 * 96 * 1024 * 2);
  short* ctxb  = (short*)alloc(896ull * 768 * 2);
  float* aout  = (float*)alloc(896ull * 768 * 4);
  float* x1    = (float*)alloc(896ull * 768 * 4);
  short* x1b   = (short*)alloc(896ull * 768 * 2);
  short* hb    = (short*)alloc(896ull * 1536 * 2);
  float* zbuf  = (float*)alloc(896ull * 768 * 4);
  (void)in_sizes; (void)n_in; (void)out_size; (void)ws_size;

  cvt_k<<<12288, 256, 0, stream>>>(hidden, hid_b);

  TcvtArgs ta;
  ta.src[0] = Wq; ta.dst[0] = WqT;               ta.Kd[0] = 768;  ta.Nd[0] = 768;
  ta.src[1] = Wk; ta.dst[1] = WkvT;              ta.Kd[1] = 768;  ta.Nd[1] = 768;
  ta.src[2] = Wv; ta.dst[2] = WkvT + 768 * 768;  ta.Kd[2] = 768;  ta.Nd[2] = 768;
  ta.src[3] = Wo; ta.dst[3] = WoT;               ta.Kd[3] = 768;  ta.Nd[3] = 768;
  ta.src[4] = W1; ta.dst[4] = W1T;               ta.Kd[4] = 768;  ta.Nd[4] = 1536;
  ta.src[5] = W2; ta.dst[5] = W2T;               ta.Kd[5] = 1536; ta.Nd[5] = 768;
  tcvt_all_k<<<dim3(24, 24, 6), 256, 0, stream>>>(ta);

  pool_k<<<896, 256, 0, stream>>>(hidden, lpos, poolf, poolb);
  gemm_k<0><<<dim3(7, 6), 256, 0, stream>>>(poolb, WqT, bq, nullptr, nullptr, qbf, nullptr, 768, 768);
  gemm_k<1><<<dim3(256, 12), 256, 0, stream>>>(hid_b, WkvT, bk, bv, nullptr, kbf, vtb, 768, 1536);
  attn_k<<<256, 256, 0, stream>>>(qbf, kbf, vtb, ctxb);
  gemm_k<2><<<dim3(7, 6), 256, 0, stream>>>(ctxb, WoT, bo, nullptr, aout, nullptr, nullptr, 768, 768);
  ln1_k<<<896, 256, 0, stream>>>(aout, poolf, g_mha, b_mha, x1, x1b);
  gemm_k<3><<<dim3(7, 12), 256, 0, stream>>>(x1b, W1T, bf1, nullptr, nullptr, hb, nullptr, 768, 1536);
  gemm_k<2><<<dim3(7, 6), 256, 0, stream>>>(hb, W2T, bf2, nullptr, zbuf, nullptr, nullptr, 1536, 768);
  ln2_k<<<896, 256, 0, stream>>>(zbuf, x1, g_ffn, b_ffn, wc, bc, dout);
  corrloss_k<<<1, 1024, 0, stream>>>(labels, dout);
}

// Round 6
// 509.674 us; speedup vs baseline: 1.0340x; 1.0340x over previous
//
#include <hip/hip_runtime.h>
#include <cstdint>
#include <cstddef>

// B=32, S=1024, H=768, L=28, NH=8, HD=96.  d_out = [loss(1), logits(896)] f32.

using short8 = __attribute__((ext_vector_type(8))) short;   // 8 bf16 = 16B
using f32x4  = __attribute__((ext_vector_type(4))) float;

__device__ __forceinline__ short f2bf(float f) {   // f32 -> bf16 RNE
  unsigned u = __builtin_bit_cast(unsigned, f);
  u = (u + 0x7fffu + ((u >> 16) & 1u)) >> 16;
  return (short)u;
}
__device__ __forceinline__ float bf2f(short s) {
  return __builtin_bit_cast(float, ((unsigned)(unsigned short)s) << 16);
}

#define MFMA16(a, b, c) __builtin_amdgcn_mfma_f32_16x16x32_bf16((a), (b), (c), 0, 0, 0)

__device__ __forceinline__ void gld16(const void* g, void* l) {
  __builtin_amdgcn_global_load_lds((const __attribute__((address_space(1))) void*)g,
                                   (__attribute__((address_space(3))) void*)l, 16, 0, 0);
}

// ---------------------------------------------------------------------------
__global__ __launch_bounds__(256) void cvt_k(const float* __restrict__ in, short* __restrict__ out) {
  size_t i = ((size_t)blockIdx.x * 256 + threadIdx.x) * 8;
  float4 a = *(const float4*)(in + i);
  float4 b = *(const float4*)(in + i + 4);
  short8 w;
  w[0]=f2bf(a.x); w[1]=f2bf(a.y); w[2]=f2bf(a.z); w[3]=f2bf(a.w);
  w[4]=f2bf(b.x); w[5]=f2bf(b.y); w[6]=f2bf(b.z); w[7]=f2bf(b.w);
  *(short8*)(out + i) = w;
}

// ---------------------------------------------------------------------------
// merged weight transpose+convert: 6 matrices in one launch. grid (24,24,6).
struct TcvtArgs { const float* src[6]; short* dst[6]; int Kd[6]; int Nd[6]; };

__global__ __launch_bounds__(256) void tcvt_all_k(TcvtArgs a) {
  const int z = blockIdx.z;
  const int K = a.Kd[z], N = a.Nd[z];
  if ((int)blockIdx.x * 64 >= N || (int)blockIdx.y * 64 >= K) return;  // block-uniform
  const float* __restrict__ in = a.src[z];
  short* __restrict__ out = a.dst[z];
  __shared__ float t[64][65];
  const int tid = threadIdx.x;
  const int bx = blockIdx.x, by = blockIdx.y;
  const int cr = tid >> 4, cc = (tid & 15) * 4;
#pragma unroll
  for (int p = 0; p < 4; p++) {
    int k = by * 64 + p * 16 + cr;
    float4 v = *(const float4*)(in + (size_t)k * N + bx * 64 + cc);
    t[p*16+cr][cc]   = v.x; t[p*16+cr][cc+1] = v.y;
    t[p*16+cr][cc+2] = v.z; t[p*16+cr][cc+3] = v.w;
  }
  __syncthreads();
  const int nl = tid >> 2, kl0 = (tid & 3) * 16;
  short8 w0, w1;
#pragma unroll
  for (int j = 0; j < 8; j++) w0[j] = f2bf(t[kl0 + j][nl]);
#pragma unroll
  for (int j = 0; j < 8; j++) w1[j] = f2bf(t[kl0 + 8 + j][nl]);
  short* op = out + (size_t)(bx * 64 + nl) * K + by * 64 + kl0;
  *(short8*)op       = w0;
  *(short8*)(op + 8) = w1;
}

// ---------------------------------------------------------------------------
__global__ __launch_bounds__(256) void pool_k(const float* __restrict__ hidden, const int* __restrict__ lp,
                                              float* __restrict__ outf, short* __restrict__ outb) {
  const int blk = blockIdx.x;            // b*28 + l
  const int b = blk / 28;
  const int start = lp[blk * 2], len = lp[blk * 2 + 1];
  const float inv = 1.f / (float)max(len, 1);
#pragma unroll
  for (int j = 0; j < 3; j++) {
    int h = threadIdx.x + j * 256;
    float s = 0.f;
    for (int q = 0; q < len; q++)
      s += hidden[((size_t)b * 1024 + start + q) * 768 + h];
    float m = s * inv;
    outf[(size_t)blk * 768 + h] = m;
    outb[(size_t)blk * 768 + h] = f2bf(m);
  }
}

// ---------------------------------------------------------------------------
// 128x128 MFMA GEMM, depth-2 prefetch (3 LDS buffers, counted vmcnt, raw s_barrier).
// 1-D grid, optional XCD swizzle (swz=1 requires gridDim.x % 8 == 0).
// A [M,K] bf16 rm, Bt [N,K] bf16 rm. 4 waves (2x2), 4x4 frags of 16x16x32 each.
// LDS: 3 bufs x (A 8KB + B 8KB) = 48KB, XOR swizzle bits4-5 ^= bits7-8 (0 conflicts, r1).
// vmcnt ladder: 4 loads/tile, 2 tiles ahead -> steady wait vmcnt(8); tail 4 -> 0.
// MODE 0: bf16 out    MODE 1: KV scatter (k[b,n,s,d], vT[b,n,d,s])
// MODE 2: f32 out     MODE 3: bf16 gelu out
template <int MODE>
__global__ __launch_bounds__(256) void gemm_k(
    const short* __restrict__ A, const short* __restrict__ Bt,
    const float* __restrict__ bias, const float* __restrict__ bias2,
    float* __restrict__ outf, short* __restrict__ outb, short* __restrict__ outb2,
    int K, int N, int nb, int swz) {
  __shared__ __align__(16) char lds[49152];
  const int tid = threadIdx.x, lane = tid & 63, wid = tid >> 6;
  const int wm = wid >> 1, wn = wid & 1;
  int id = blockIdx.x;
  if (swz) { int cpx = (int)gridDim.x >> 3; id = (id & 7) * cpx + (id >> 3); }  // XCD chunks (T1)
  const int m0 = (id / nb) * 128, n0 = (id % nb) * 128;
  const int lr = lane & 15, lg = lane >> 4;

  int aoff = (wm * 64 + lr) * 64 + lg * 16;
  aoff ^= ((aoff >> 7) & 3) << 4;
  int boff = (wn * 64 + lr) * 64 + lg * 16;
  boff ^= ((boff >> 7) & 3) << 4;
  boff += 8192;

  // staging: LDS linear dest d -> logical o = swz(d) -> global (row, col)
  const int d0 = wid * 1024 + lane * 16;
  const int d1 = d0 + 4096;
  const int o0 = d0 ^ (((d0 >> 7) & 3) << 4);
  const int o1 = d1 ^ (((d1 >> 7) & 3) << 4);
  const int r0 = o0 >> 6, c0 = (o0 & 63) >> 1;
  const int r1 = o1 >> 6, c1 = (o1 & 63) >> 1;
  const short* pA0 = A + (size_t)(m0 + r0) * K + c0;
  const short* pA1 = A + (size_t)(m0 + r1) * K + c1;
  const short* pB0 = Bt + (size_t)(n0 + r0) * K + c0;
  const short* pB1 = Bt + (size_t)(n0 + r1) * K + c1;

  f32x4 acc[4][4];
  const f32x4 zf = {0.f, 0.f, 0.f, 0.f};
#pragma unroll
  for (int i = 0; i < 4; i++)
#pragma unroll
    for (int j = 0; j < 4; j++) acc[i][j] = zf;

  auto STAGE = [&](int buf, int kk) {
    char* db = lds + buf * 16384;
    gld16(pA0 + kk, db + wid * 1024);
    gld16(pA1 + kk, db + 4096 + wid * 1024);
    gld16(pB0 + kk, db + 8192 + wid * 1024);
    gld16(pB1 + kk, db + 12288 + wid * 1024);
  };

  STAGE(0, 0);                                   // prologue: tiles 0,1 in flight (8 loads)
  STAGE(1, 32);
  int cur = 0;
  for (int k0 = 0; k0 < K; k0 += 32) {
    __builtin_amdgcn_sched_barrier(0);           // keep STAGE below prev iter's barrier
    if (k0 + 64 < K) {
      int nxt = cur + 2; if (nxt >= 3) nxt -= 3;
      STAGE(nxt, k0 + 64);                       // outstanding: 12
      asm volatile("s_waitcnt vmcnt(8)" ::: "memory");   // tile k0's 4 loads done
    } else if (k0 + 32 < K) {
      asm volatile("s_waitcnt vmcnt(4)" ::: "memory");   // tail: 8 outstanding
    } else {
      asm volatile("s_waitcnt vmcnt(0)" ::: "memory");   // last tile: full drain
    }
    __builtin_amdgcn_s_barrier();                // raw barrier: no vmcnt(0) drain
    __builtin_amdgcn_sched_barrier(0);           // no ds_read hoisted above barrier
    const char* bb_ = lds + cur * 16384;
    short8 af[4], bq8[4];
#pragma unroll
    for (int i = 0; i < 4; i++) af[i] = *(const short8*)(bb_ + aoff + i * 1024);
#pragma unroll
    for (int j = 0; j < 4; j++) bq8[j] = *(const short8*)(bb_ + boff + j * 1024);
#pragma unroll
    for (int i = 0; i < 4; i++)
#pragma unroll
      for (int j = 0; j < 4; j++)
        acc[i][j] = MFMA16(af[i], bq8[j], acc[i][j]);
    __builtin_amdgcn_sched_barrier(0);
    __builtin_amdgcn_s_barrier();                // all reads of buf[cur] done (lgkm drained
    cur = (cur + 1 == 3) ? 0 : cur + 1;          //  before first MFMA, hence before barrier)
  }

  if constexpr (MODE == 1) {
    const int b = m0 >> 10;
    const int sb = (m0 & 1023) + wm * 64;
#pragma unroll
    for (int j = 0; j < 4; j++) {
      int c = n0 + wn * 64 + j * 16 + lr;
      bool isv = c >= 768;                       // uniform per wave
      int c7 = isv ? c - 768 : c;
      int nh = c7 / 96;
      int dd = c7 - nh * 96;
      float bb = isv ? bias2[c7] : bias[c7];
      size_t base = isv ? ((size_t)((b * 8 + nh) * 96 + dd)) * 1024
                        : (size_t)(b * 8 + nh) * 98304 + dd;
      short* op = isv ? outb2 : outb;
#pragma unroll
      for (int i = 0; i < 4; i++) {
        int s0 = sb + i * 16 + lg * 4;
#pragma unroll
        for (int t = 0; t < 4; t++) {
          short v = f2bf(acc[i][j][t] + bb);
          if (isv) op[base + s0 + t] = v;                 // vT[b,n,d,s] (8B merged)
          else     op[base + (size_t)(s0 + t) * 96] = v;  // k[b,n,s,d]
        }
      }
    }
  } else {
    const int rb = m0 + wm * 64;
    const int cb = n0 + wn * 64;
#pragma unroll
    for (int j = 0; j < 4; j++) {
      int c = cb + j * 16 + lr;
      float bb = bias[c];
#pragma unroll
      for (int i = 0; i < 4; i++) {
        int r = rb + i * 16 + lg * 4;
#pragma unroll
        for (int t = 0; t < 4; t++) {
          float v = acc[i][j][t] + bb;
          if constexpr (MODE == 0) {
            outb[(size_t)(r + t) * N + c] = f2bf(v);
          } else if constexpr (MODE == 2) {
            outf[(size_t)(r + t) * N + c] = v;
          } else {
            float ge = v * 0.5f * (1.f + erff(v * 0.70710678118654752f));
            outb[(size_t)(r + t) * N + c] = f2bf(ge);
          }
        }
      }
    }
  }
}

// ---------------------------------------------------------------------------
// cross-attention, one block per (b,head). Scores in LDS as bf16 [32][1040]
// (66.5 KB -> 2 blocks/CU). Phase-3 P fragments are direct short8 LDS reads.
#define SROWS 1040
__global__ __launch_bounds__(256, 2) void attn_k(
    const short* __restrict__ qb, const short* __restrict__ kb,
    const short* __restrict__ vtb, short* __restrict__ ctxb) {
  __shared__ __align__(16) short sc[32 * SROWS];     // 66560 B
  __shared__ float rowsum[28];
  const int b = blockIdx.x >> 3, n = blockIdx.x & 7;
  const int tid = threadIdx.x, lane = tid & 63, wid = tid >> 6;
  const int lr = lane & 15, lg = lane >> 4;
  const float rs = 0.10206207261596575f;             // 1/sqrt(96)
  const f32x4 zf = {0.f, 0.f, 0.f, 0.f};
  const short8 z8 = {0, 0, 0, 0, 0, 0, 0, 0};

  short8 aq[2][3];                                   // Q fragments, rows >= 28 zero
#pragma unroll
  for (int mt = 0; mt < 2; mt++) {
    int row = mt * 16 + lr;
#pragma unroll
    for (int kk = 0; kk < 3; kk++)
      aq[mt][kk] = (row < 28)
          ? *(const short8*)(qb + (size_t)(b * 28 + row) * 768 + n * 96 + kk * 32 + lg * 8)
          : z8;
  }

  // phase 1: scores -> bf16 LDS. wave w owns s in [w*256, w*256+256)
  const short* kbase = kb + (size_t)(b * 8 + n) * 98304;
#pragma unroll 2
  for (int st = 0; st < 16; st++) {
    int s0 = wid * 256 + st * 16;
    f32x4 a0 = zf, a1 = zf;
#pragma unroll
    for (int kk = 0; kk < 3; kk++) {
      short8 bk8 = *(const short8*)(kbase + (size_t)(s0 + lr) * 96 + kk * 32 + lg * 8);
      a0 = MFMA16(aq[0][kk], bk8, a0);
      a1 = MFMA16(aq[1][kk], bk8, a1);
    }
#pragma unroll
    for (int t = 0; t < 4; t++) {
      sc[(lg * 4 + t) * SROWS + s0 + lr]      = f2bf(a0[t] * rs);
      sc[(16 + lg * 4 + t) * SROWS + s0 + lr] = f2bf(a1[t] * rs);
    }
  }
  __syncthreads();

  // phase 2: softmax rows (unnormalized exp, bf16 writeback). wave w rows [7w,7w+7)
  for (int rr = 0; rr < 7; rr++) {
    int r = wid * 7 + rr;
    short* rp = sc + r * SROWS;
    float v[16];
    float mx = -3.0e38f;
#pragma unroll
    for (int t = 0; t < 16; t++) { v[t] = bf2f(rp[lane + t * 64]); mx = fmaxf(mx, v[t]); }
#pragma unroll
    for (int o = 32; o > 0; o >>= 1) mx = fmaxf(mx, __shfl_xor(mx, o));
    float sm = 0.f;
#pragma unroll
    for (int t = 0; t < 16; t++) { v[t] = __expf(v[t] - mx); sm += v[t]; }
#pragma unroll
    for (int o = 32; o > 0; o >>= 1) sm += __shfl_xor(sm, o);
#pragma unroll
    for (int t = 0; t < 16; t++) rp[lane + t * 64] = f2bf(v[t]);
    if (lane == 0) rowsum[r] = sm;
  }
  // rows 28..31 hold raw score 0 (zeroed Q rows) == P 0: no explicit zeroing needed
  __syncthreads();

  // phase 3: ctx partial = P @ V over this wave's s-range
  f32x4 acc2[2][6];
#pragma unroll
  for (int mt = 0; mt < 2; mt++)
#pragma unroll
    for (int nt = 0; nt < 6; nt++) acc2[mt][nt] = zf;
  const short* vbase = vtb + (size_t)(b * 8 + n) * 98304;
#pragma unroll 2
  for (int ks = 0; ks < 8; ks++) {
    int s0 = wid * 256 + ks * 32;
    short8 pa0 = *(const short8*)(sc + (size_t)lr * SROWS + s0 + lg * 8);
    short8 pa1 = *(const short8*)(sc + (size_t)(16 + lr) * SROWS + s0 + lg * 8);
#pragma unroll
    for (int nt = 0; nt < 6; nt++) {
      short8 bv8 = *(const short8*)(vbase + (size_t)(nt * 16 + lr) * 1024 + s0 + lg * 8);
      acc2[0][nt] = MFMA16(pa0, bv8, acc2[0][nt]);
      acc2[1][nt] = MFMA16(pa1, bv8, acc2[1][nt]);
    }
  }
  __syncthreads();                                   // sc reads done; reuse as f32 partials
  float* part = (float*)sc;                          // [4][32][96] = 49152 B
#pragma unroll
  for (int mt = 0; mt < 2; mt++)
#pragma unroll
    for (int nt = 0; nt < 6; nt++)
#pragma unroll
      for (int t = 0; t < 4; t++)
        part[wid * 3072 + (mt * 16 + lg * 4 + t) * 96 + nt * 16 + lr] = acc2[mt][nt][t];
  __syncthreads();
  for (int idx = tid; idx < 2688; idx += 256) {
    int l = idx / 96, d = idx - (idx / 96) * 96;
    float s = part[idx] + part[3072 + idx] + part[6144 + idx] + part[9216 + idx];
    ctxb[(size_t)(b * 28 + l) * 768 + n * 96 + d] = f2bf(s / rowsum[l]);
  }
}

// ---------------------------------------------------------------------------
__device__ __forceinline__ float blk_sum4(float v, float* red) {
  const int lane = threadIdx.x & 63, wid = threadIdx.x >> 6;
#pragma unroll
  for (int o = 32; o > 0; o >>= 1) v += __shfl_xor(v, o);
  __syncthreads();
  if (lane == 0) red[wid] = v;
  __syncthreads();
  return red[0] + red[1] + red[2] + red[3];
}

__global__ __launch_bounds__(256) void ln1_k(const float* __restrict__ ao, const float* __restrict__ lh,
                                             const float* __restrict__ g, const float* __restrict__ bb,
                                             float* __restrict__ x1, short* __restrict__ x1b) {
  __shared__ float red[4];
  const int row = blockIdx.x, tid = threadIdx.x;
  const size_t base = (size_t)row * 768;
  float x[3], s1 = 0.f, s2 = 0.f;
#pragma unroll
  for (int j = 0; j < 3; j++) {
    int c = tid + j * 256;
    x[j] = ao[base + c] + lh[base + c];
    s1 += x[j]; s2 += x[j] * x[j];
  }
  s1 = blk_sum4(s1, red);
  s2 = blk_sum4(s2, red);
  float mu = s1 * (1.f / 768.f);
  float inv = rsqrtf(s2 * (1.f / 768.f) - mu * mu + 1e-5f);
#pragma unroll
  for (int j = 0; j < 3; j++) {
    int c = tid + j * 256;
    float y = (x[j] - mu) * inv * g[c] + bb[c];
    x1[base + c] = y;
    x1b[base + c] = f2bf(y);
  }
}

__global__ __launch_bounds__(256) void ln2_k(const float* __restrict__ z, const float* __restrict__ x1,
                                             const float* __restrict__ g, const float* __restrict__ bb,
                                             const float* __restrict__ wc, const float* __restrict__ bc,
                                             float* __restrict__ dout) {
  __shared__ float red[4];
  const int row = blockIdx.x, tid = threadIdx.x;
  const size_t base = (size_t)row * 768;
  float x[3], s1 = 0.f, s2 = 0.f;
#pragma unroll
  for (int j = 0; j < 3; j++) {
    int c = tid + j * 256;
    x[j] = z[base + c] + x1[base + c];
    s1 += x[j]; s2 += x[j] * x[j];
  }
  s1 = blk_sum4(s1, red);
  s2 = blk_sum4(s2, red);
  float mu = s1 * (1.f / 768.f);
  float inv = rsqrtf(s2 * (1.f / 768.f) - mu * mu + 1e-5f);
  float dacc = 0.f;
#pragma unroll
  for (int j = 0; j < 3; j++) {
    int c = tid + j * 256;
    float y = (x[j] - mu) * inv * g[c] + bb[c];
    dacc += y * wc[c];
  }
  dacc = blk_sum4(dacc, red);
  if (tid == 0) dout[1 + row] = dacc + bc[0];
}

// merged pair-loss + bce + final loss: one block, 1024 threads.
__global__ __launch_bounds__(1024) void corrloss_k(const float* __restrict__ labels,
                                                   float* __restrict__ dout) {
  __shared__ float lg[896], lb[896];
  __shared__ float red[64];
  const int tid = threadIdx.x;
  if (tid < 896) { lg[tid] = dout[1 + tid]; lb[tid] = labels[tid]; }
  __syncthreads();
  float bce = 0.f, pos = 0.f, neg = 0.f;
  if (tid < 896) {
    float l = lg[tid], y = lb[tid];
    bce = fmaxf(l, 0.f) - l * y + log1pf(expf(-fabsf(l)));
    pos = y; neg = 1.f - y;
  }
  float a = 0.f;
  const int isub = tid >> 5, jsub = tid & 31;
  for (int ib = 0; ib < 28; ib++) {
    int i = ib * 32 + isub;
    if (lb[i] == 1.f) {
      float li = lg[i];
#pragma unroll 4
      for (int jb = 0; jb < 28; jb++) {
        int j = jsub + jb * 32;
        if (lb[j] == 0.f) a += fmaxf(lg[j] - li + 0.3f, 0.f);
      }
    }
  }
#pragma unroll
  for (int o = 32; o > 0; o >>= 1) {
    bce += __shfl_xor(bce, o); pos += __shfl_xor(pos, o);
    neg += __shfl_xor(neg, o); a   += __shfl_xor(a, o);
  }
  const int w = tid >> 6;
  if ((tid & 63) == 0) { red[w] = bce; red[16 + w] = pos; red[32 + w] = neg; red[48 + w] = a; }
  __syncthreads();
  if (tid == 0) {
    float sb = 0.f, sp = 0.f, sn = 0.f, sa = 0.f;
#pragma unroll
    for (int k = 0; k < 16; k++) { sb += red[k]; sp += red[16 + k]; sn += red[32 + k]; sa += red[48 + k]; }
    float denom = sp * sn;
    float corr = denom > 0.f ? sa / fmaxf(denom, 1.f) : 0.f;
    dout[0] = 0.8f * sb * (1.f / 896.f) + 0.2f * corr;
  }
}

// ---------------------------------------------------------------------------
extern "C" void kernel_launch(void* const* d_in, const int* in_sizes, int n_in,
                              void* d_out, int out_size, void* d_ws, size_t ws_size,
                              hipStream_t stream) {
  const float* hidden = (const float*)d_in[0];
  const float* labels = (const float*)d_in[1];
  const int*   lpos   = (const int*)d_in[2];
  const float* Wq = (const float*)d_in[3];  const float* bq = (const float*)d_in[4];
  const float* Wk = (const float*)d_in[5];  const float* bk = (const float*)d_in[6];
  const float* Wv = (const float*)d_in[7];  const float* bv = (const float*)d_in[8];
  const float* Wo = (const float*)d_in[9];  const float* bo = (const float*)d_in[10];
  const float* g_mha = (const float*)d_in[11]; const float* b_mha = (const float*)d_in[12];
  const float* W1 = (const float*)d_in[13]; const float* bf1 = (const float*)d_in[14];
  const float* W2 = (const float*)d_in[15]; const float* bf2 = (const float*)d_in[16];
  const float* g_ffn = (const float*)d_in[17]; const float* b_ffn = (const float*)d_in[18];
  const float* wc = (const float*)d_in[19]; const float* bc = (const float*)d_in[20];
  float* dout = (float*)d_out;

  char* ws = (char*)d_ws;
  size_t off = 0;
  auto alloc = [&](size_t bytes) { char* p = ws + off; off += (bytes + 255) & ~(size_t)255; return p; };
  short* hid_b = (short*)alloc(32ull * 1024 * 768 * 2);
  short* WqT   = (short*)alloc(768ull * 768 * 2);
  short* WkvT  = (short*)alloc(1536ull * 768 * 2);
  short* WoT   = (short*)alloc(768ull * 768 * 2);
  short* W1T   = (short*)alloc(1536ull * 768 * 2);
  short* W2T   = (short*)alloc(768ull * 1536 * 2);
  float* poolf = (float*)alloc(896ull * 768 * 4);
  short* poolb = (short*)alloc(896ull * 768 * 2);
  short* qbf   = (short*)alloc(896ull * 768 * 2);
  short* kbf   = (short*)alloc(32ull * 8 * 1024 * 96 * 2);
  short* vtb   = (short*)alloc(32ull * 8 * 96 * 1024 * 2);
  short* ctxb  = (short*)alloc(896ull * 768 * 2);
  float* aout  = (float*)alloc(896ull * 768 * 4);
  float* x1    = (float*)alloc(896ull * 768 * 4);
  short* x1b   = (short*)alloc(896ull * 768 * 2);
  short* hb    = (short*)alloc(896ull * 1536 * 2);
  float* zbuf  = (float*)alloc(896ull * 768 * 4);
  (void)in_sizes; (void)n_in; (void)out_size; (void)ws_size;

  cvt_k<<<12288, 256, 0, stream>>>(hidden, hid_b);

  TcvtArgs ta;
  ta.src[0] = Wq; ta.dst[0] = WqT;               ta.Kd[0] = 768;  ta.Nd[0] = 768;
  ta.src[1] = Wk; ta.dst[1] = WkvT;              ta.Kd[1] = 768;  ta.Nd[1] = 768;
  ta.src[2] = Wv; ta.dst[2] = WkvT + 768 * 768;  ta.Kd[2] = 768;  ta.Nd[2] = 768;
  ta.src[3] = Wo; ta.dst[3] = WoT;               ta.Kd[3] = 768;  ta.Nd[3] = 768;
  ta.src[4] = W1; ta.dst[4] = W1T;               ta.Kd[4] = 768;  ta.Nd[4] = 1536;
  ta.src[5] = W2; ta.dst[5] = W2T;               ta.Kd[5] = 1536; ta.Nd[5] = 768;
  tcvt_all_k<<<dim3(24, 24, 6), 256, 0, stream>>>(ta);

  pool_k<<<896, 256, 0, stream>>>(hidden, lpos, poolf, poolb);
  // q = label_hidden @ Wq + bq  (42 blocks: 7m x 6n)
  gemm_k<0><<<42, 256, 0, stream>>>(poolb, WqT, bq, nullptr, nullptr, qbf, nullptr, 768, 768, 6, 0);
  // k,v = hidden @ [Wk|Wv]  (3072 blocks: 256m x 12n, XCD-swizzled)
  gemm_k<1><<<3072, 256, 0, stream>>>(hid_b, WkvT, bk, bv, nullptr, kbf, vtb, 768, 1536, 12, 1);
  attn_k<<<256, 256, 0, stream>>>(qbf, kbf, vtb, ctxb);
  // attn_out = ctx @ Wo + bo
  gemm_k<2><<<42, 256, 0, stream>>>(ctxb, WoT, bo, nullptr, aout, nullptr, nullptr, 768, 768, 6, 0);
  ln1_k<<<896, 256, 0, stream>>>(aout, poolf, g_mha, b_mha, x1, x1b);
  // h = gelu(x1 @ W1 + bf1)  (84 blocks: 7m x 12n)
  gemm_k<3><<<84, 256, 0, stream>>>(x1b, W1T, bf1, nullptr, nullptr, hb, nullptr, 768, 1536, 12, 0);
  // z = h @ W2 + bf2
  gemm_k<2><<<42, 256, 0, stream>>>(hb, W2T, bf2, nullptr, zbuf, nullptr, nullptr, 1536, 768, 6, 0);
  ln2_k<<<896, 256, 0, stream>>>(zbuf, x1, g_ffn, b_ffn, wc, bc, dout);
  corrloss_k<<<1, 1024, 0, stream>>>(labels, dout);
}

// Round 7
// 504.686 us; speedup vs baseline: 1.0443x; 1.0099x over previous
//
#include <hip/hip_runtime.h>
#include <cstdint>
#include <cstddef>

// B=32, S=1024, H=768, L=28, NH=8, HD=96.  d_out = [loss(1), logits(896)] f32.

using short8 = __attribute__((ext_vector_type(8))) short;   // 8 bf16 = 16B
using f32x4  = __attribute__((ext_vector_type(4))) float;

__device__ __forceinline__ short f2bf(float f) {   // f32 -> bf16 RNE
  unsigned u = __builtin_bit_cast(unsigned, f);
  u = (u + 0x7fffu + ((u >> 16) & 1u)) >> 16;
  return (short)u;
}
__device__ __forceinline__ float bf2f(short s) {
  return __builtin_bit_cast(float, ((unsigned)(unsigned short)s) << 16);
}

#define MFMA16(a, b, c) __builtin_amdgcn_mfma_f32_16x16x32_bf16((a), (b), (c), 0, 0, 0)

__device__ __forceinline__ void gld16(const void* g, void* l) {
  __builtin_amdgcn_global_load_lds((const __attribute__((address_space(1))) void*)g,
                                   (__attribute__((address_space(3))) void*)l, 16, 0, 0);
}

// ---------------------------------------------------------------------------
__global__ __launch_bounds__(256) void cvt_k(const float* __restrict__ in, short* __restrict__ out) {
  size_t i = ((size_t)blockIdx.x * 256 + threadIdx.x) * 8;
  float4 a = *(const float4*)(in + i);
  float4 b = *(const float4*)(in + i + 4);
  short8 w;
  w[0]=f2bf(a.x); w[1]=f2bf(a.y); w[2]=f2bf(a.z); w[3]=f2bf(a.w);
  w[4]=f2bf(b.x); w[5]=f2bf(b.y); w[6]=f2bf(b.z); w[7]=f2bf(b.w);
  *(short8*)(out + i) = w;
}

// ---------------------------------------------------------------------------
// merged weight transpose+convert: 6 matrices in one launch. grid (24,24,6).
struct TcvtArgs { const float* src[6]; short* dst[6]; int Kd[6]; int Nd[6]; };

__global__ __launch_bounds__(256) void tcvt_all_k(TcvtArgs a) {
  const int z = blockIdx.z;
  const int K = a.Kd[z], N = a.Nd[z];
  if ((int)blockIdx.x * 64 >= N || (int)blockIdx.y * 64 >= K) return;  // block-uniform
  const float* __restrict__ in = a.src[z];
  short* __restrict__ out = a.dst[z];
  __shared__ float t[64][65];
  const int tid = threadIdx.x;
  const int bx = blockIdx.x, by = blockIdx.y;
  const int cr = tid >> 4, cc = (tid & 15) * 4;
#pragma unroll
  for (int p = 0; p < 4; p++) {
    int k = by * 64 + p * 16 + cr;
    float4 v = *(const float4*)(in + (size_t)k * N + bx * 64 + cc);
    t[p*16+cr][cc]   = v.x; t[p*16+cr][cc+1] = v.y;
    t[p*16+cr][cc+2] = v.z; t[p*16+cr][cc+3] = v.w;
  }
  __syncthreads();
  const int nl = tid >> 2, kl0 = (tid & 3) * 16;
  short8 w0, w1;
#pragma unroll
  for (int j = 0; j < 8; j++) w0[j] = f2bf(t[kl0 + j][nl]);
#pragma unroll
  for (int j = 0; j < 8; j++) w1[j] = f2bf(t[kl0 + 8 + j][nl]);
  short* op = out + (size_t)(bx * 64 + nl) * K + by * 64 + kl0;
  *(short8*)op       = w0;
  *(short8*)(op + 8) = w1;
}

// ---------------------------------------------------------------------------
__global__ __launch_bounds__(256) void pool_k(const float* __restrict__ hidden, const int* __restrict__ lp,
                                              float* __restrict__ outf, short* __restrict__ outb) {
  const int blk = blockIdx.x;            // b*28 + l
  const int b = blk / 28;
  const int start = lp[blk * 2], len = lp[blk * 2 + 1];
  const float inv = 1.f / (float)max(len, 1);
#pragma unroll
  for (int j = 0; j < 3; j++) {
    int h = threadIdx.x + j * 256;
    float s = 0.f;
    for (int q = 0; q < len; q++)
      s += hidden[((size_t)b * 1024 + start + q) * 768 + h];
    float m = s * inv;
    outf[(size_t)blk * 768 + h] = m;
    outb[(size_t)blk * 768 + h] = f2bf(m);
  }
}

// ---------------------------------------------------------------------------
// 128x64 MFMA GEMM, depth-2 prefetch (3 LDS bufs, counted vmcnt, raw s_barrier).
// Tile shrunk from 128x128 (r6) to raise occupancy: acc 64->32 AGPR, LDS 48->36KB
// -> ~4 blocks/CU (was 2-3). 4 waves (2m x 2n), each 64x32 out (4x2 frags).
// 1-D grid, optional XCD swizzle (swz=1 requires gridDim.x % 8 == 0).
// LDS/buf: A 8KB + B 4KB; XOR swizzle bits4-5 ^= bits7-8 (0 conflicts, r1/r6).
// 3 gld16/tile -> vmcnt ladder 6/3/0 (3 loads x 2 tiles in flight).
// MODE 0: bf16 out    MODE 1: KV scatter (k[b,n,s,d], vT[b,n,d,s])
// MODE 2: f32 out     MODE 3: bf16 gelu out
template <int MODE>
__global__ __launch_bounds__(256) void gemm_k(
    const short* __restrict__ A, const short* __restrict__ Bt,
    const float* __restrict__ bias, const float* __restrict__ bias2,
    float* __restrict__ outf, short* __restrict__ outb, short* __restrict__ outb2,
    int K, int N, int nb, int swz) {
  __shared__ __align__(16) char lds[36864];
  const int tid = threadIdx.x, lane = tid & 63, wid = tid >> 6;
  const int wm = wid >> 1, wn = wid & 1;
  int id = blockIdx.x;
  if (swz) { int cpx = (int)gridDim.x >> 3; id = (id & 7) * cpx + (id >> 3); }  // XCD chunks (T1)
  const int m0 = (id / nb) * 128, n0 = (id % nb) * 64;
  const int lr = lane & 15, lg = lane >> 4;

  int aoff = (wm * 64 + lr) * 64 + lg * 16;
  aoff ^= ((aoff >> 7) & 3) << 4;
  int boff = (wn * 32 + lr) * 64 + lg * 16;
  boff ^= ((boff >> 7) & 3) << 4;
  boff += 8192;                                  // B region within buffer

  // staging: LDS linear dest d -> logical o = swz(d) -> global (row, col)
  const int d0 = wid * 1024 + lane * 16;         // A first 4KB
  const int d1 = d0 + 4096;                      // A second 4KB
  const int o0 = d0 ^ (((d0 >> 7) & 3) << 4);
  const int o1 = d1 ^ (((d1 >> 7) & 3) << 4);
  const int ob = d0 ^ (((d0 >> 7) & 3) << 4);    // B 4KB (same lane->offset map)
  const int r0 = o0 >> 6, c0 = (o0 & 63) >> 1;
  const int r1 = o1 >> 6, c1 = (o1 & 63) >> 1;
  const int rb_ = ob >> 6, cb_ = (ob & 63) >> 1;
  const short* pA0 = A + (size_t)(m0 + r0) * K + c0;
  const short* pA1 = A + (size_t)(m0 + r1) * K + c1;
  const short* pB0 = Bt + (size_t)(n0 + rb_) * K + cb_;

  f32x4 acc[4][2];
  const f32x4 zf = {0.f, 0.f, 0.f, 0.f};
#pragma unroll
  for (int i = 0; i < 4; i++)
#pragma unroll
    for (int j = 0; j < 2; j++) acc[i][j] = zf;

  auto STAGE = [&](int buf, int kk) {
    char* db = lds + buf * 12288;
    gld16(pA0 + kk, db + wid * 1024);
    gld16(pA1 + kk, db + 4096 + wid * 1024);
    gld16(pB0 + kk, db + 8192 + wid * 1024);
  };

  STAGE(0, 0);                                   // prologue: tiles 0,1 in flight (6 loads)
  STAGE(1, 32);
  int cur = 0;
  for (int k0 = 0; k0 < K; k0 += 32) {
    __builtin_amdgcn_sched_barrier(0);           // keep STAGE below prev iter's barrier
    if (k0 + 64 < K) {
      int nxt = cur + 2; if (nxt >= 3) nxt -= 3;
      STAGE(nxt, k0 + 64);                       // outstanding: 9
      asm volatile("s_waitcnt vmcnt(6)" ::: "memory");   // tile k0's 3 loads done
    } else if (k0 + 32 < K) {
      asm volatile("s_waitcnt vmcnt(3)" ::: "memory");   // tail: 6 outstanding
    } else {
      asm volatile("s_waitcnt vmcnt(0)" ::: "memory");   // last tile: full drain
    }
    __builtin_amdgcn_s_barrier();                // raw barrier: no vmcnt(0) drain
    __builtin_amdgcn_sched_barrier(0);           // no ds_read hoisted above barrier
    const char* bb_ = lds + cur * 12288;
    short8 af[4], bq8[2];
#pragma unroll
    for (int i = 0; i < 4; i++) af[i] = *(const short8*)(bb_ + aoff + i * 1024);
#pragma unroll
    for (int j = 0; j < 2; j++) bq8[j] = *(const short8*)(bb_ + boff + j * 1024);
#pragma unroll
    for (int i = 0; i < 4; i++)
#pragma unroll
      for (int j = 0; j < 2; j++)
        acc[i][j] = MFMA16(af[i], bq8[j], acc[i][j]);
    __builtin_amdgcn_sched_barrier(0);
    __builtin_amdgcn_s_barrier();                // all reads of buf[cur] done (lgkm drained
    cur = (cur + 1 == 3) ? 0 : cur + 1;          //  before first MFMA, hence before barrier)
  }

  if constexpr (MODE == 1) {
    const int b = m0 >> 10;
    const int sb = (m0 & 1023) + wm * 64;
#pragma unroll
    for (int j = 0; j < 2; j++) {
      int c = n0 + wn * 32 + j * 16 + lr;
      bool isv = c >= 768;                       // uniform per (block,wave)
      int c7 = isv ? c - 768 : c;
      int nh = c7 / 96;
      int dd = c7 - nh * 96;
      float bb = isv ? bias2[c7] : bias[c7];
      size_t base = isv ? ((size_t)((b * 8 + nh) * 96 + dd)) * 1024
                        : (size_t)(b * 8 + nh) * 98304 + dd;
      short* op = isv ? outb2 : outb;
#pragma unroll
      for (int i = 0; i < 4; i++) {
        int s0 = sb + i * 16 + lg * 4;
#pragma unroll
        for (int t = 0; t < 4; t++) {
          short v = f2bf(acc[i][j][t] + bb);
          if (isv) op[base + s0 + t] = v;                 // vT[b,n,d,s] (8B merged)
          else     op[base + (size_t)(s0 + t) * 96] = v;  // k[b,n,s,d]
        }
      }
    }
  } else {
    const int rb = m0 + wm * 64;
    const int cb = n0 + wn * 32;
#pragma unroll
    for (int j = 0; j < 2; j++) {
      int c = cb + j * 16 + lr;
      float bb = bias[c];
#pragma unroll
      for (int i = 0; i < 4; i++) {
        int r = rb + i * 16 + lg * 4;
#pragma unroll
        for (int t = 0; t < 4; t++) {
          float v = acc[i][j][t] + bb;
          if constexpr (MODE == 0) {
            outb[(size_t)(r + t) * N + c] = f2bf(v);
          } else if constexpr (MODE == 2) {
            outf[(size_t)(r + t) * N + c] = v;
          } else {
            float ge = v * 0.5f * (1.f + erff(v * 0.70710678118654752f));
            outb[(size_t)(r + t) * N + c] = f2bf(ge);
          }
        }
      }
    }
  }
}

// ---------------------------------------------------------------------------
// cross-attention, one block per (b,head). Scores in LDS as bf16 [32][1040]
// (66.5 KB -> 2 blocks/CU). Phase-3 P fragments are direct short8 LDS reads.
#define SROWS 1040
__global__ __launch_bounds__(256, 2) void attn_k(
    const short* __restrict__ qb, const short* __restrict__ kb,
    const short* __restrict__ vtb, short* __restrict__ ctxb) {
  __shared__ __align__(16) short sc[32 * SROWS];     // 66560 B
  __shared__ float rowsum[28];
  const int b = blockIdx.x >> 3, n = blockIdx.x & 7;
  const int tid = threadIdx.x, lane = tid & 63, wid = tid >> 6;
  const int lr = lane & 15, lg = lane >> 4;
  const float rs = 0.10206207261596575f;             // 1/sqrt(96)
  const f32x4 zf = {0.f, 0.f, 0.f, 0.f};
  const short8 z8 = {0, 0, 0, 0, 0, 0, 0, 0};

  short8 aq[2][3];                                   // Q fragments, rows >= 28 zero
#pragma unroll
  for (int mt = 0; mt < 2; mt++) {
    int row = mt * 16 + lr;
#pragma unroll
    for (int kk = 0; kk < 3; kk++)
      aq[mt][kk] = (row < 28)
          ? *(const short8*)(qb + (size_t)(b * 28 + row) * 768 + n * 96 + kk * 32 + lg * 8)
          : z8;
  }

  // phase 1: scores -> bf16 LDS. wave w owns s in [w*256, w*256+256)
  const short* kbase = kb + (size_t)(b * 8 + n) * 98304;
#pragma unroll 2
  for (int st = 0; st < 16; st++) {
    int s0 = wid * 256 + st * 16;
    f32x4 a0 = zf, a1 = zf;
#pragma unroll
    for (int kk = 0; kk < 3; kk++) {
      short8 bk8 = *(const short8*)(kbase + (size_t)(s0 + lr) * 96 + kk * 32 + lg * 8);
      a0 = MFMA16(aq[0][kk], bk8, a0);
      a1 = MFMA16(aq[1][kk], bk8, a1);
    }
#pragma unroll
    for (int t = 0; t < 4; t++) {
      sc[(lg * 4 + t) * SROWS + s0 + lr]      = f2bf(a0[t] * rs);
      sc[(16 + lg * 4 + t) * SROWS + s0 + lr] = f2bf(a1[t] * rs);
    }
  }
  __syncthreads();

  // phase 2: softmax rows (unnormalized exp, bf16 writeback). wave w rows [7w,7w+7)
  for (int rr = 0; rr < 7; rr++) {
    int r = wid * 7 + rr;
    short* rp = sc + r * SROWS;
    float v[16];
    float mx = -3.0e38f;
#pragma unroll
    for (int t = 0; t < 16; t++) { v[t] = bf2f(rp[lane + t * 64]); mx = fmaxf(mx, v[t]); }
#pragma unroll
    for (int o = 32; o > 0; o >>= 1) mx = fmaxf(mx, __shfl_xor(mx, o));
    float sm = 0.f;
#pragma unroll
    for (int t = 0; t < 16; t++) { v[t] = __expf(v[t] - mx); sm += v[t]; }
#pragma unroll
    for (int o = 32; o > 0; o >>= 1) sm += __shfl_xor(sm, o);
#pragma unroll
    for (int t = 0; t < 16; t++) rp[lane + t * 64] = f2bf(v[t]);
    if (lane == 0) rowsum[r] = sm;
  }
  // rows 28..31 hold raw score 0 (zeroed Q rows) == P 0: no explicit zeroing needed
  __syncthreads();

  // phase 3: ctx partial = P @ V over this wave's s-range
  f32x4 acc2[2][6];
#pragma unroll
  for (int mt = 0; mt < 2; mt++)
#pragma unroll
    for (int nt = 0; nt < 6; nt++) acc2[mt][nt] = zf;
  const short* vbase = vtb + (size_t)(b * 8 + n) * 98304;
#pragma unroll 2
  for (int ks = 0; ks < 8; ks++) {
    int s0 = wid * 256 + ks * 32;
    short8 pa0 = *(const short8*)(sc + (size_t)lr * SROWS + s0 + lg * 8);
    short8 pa1 = *(const short8*)(sc + (size_t)(16 + lr) * SROWS + s0 + lg * 8);
#pragma unroll
    for (int nt = 0; nt < 6; nt++) {
      short8 bv8 = *(const short8*)(vbase + (size_t)(nt * 16 + lr) * 1024 + s0 + lg * 8);
      acc2[0][nt] = MFMA16(pa0, bv8, acc2[0][nt]);
      acc2[1][nt] = MFMA16(pa1, bv8, acc2[1][nt]);
    }
  }
  __syncthreads();                                   // sc reads done; reuse as f32 partials
  float* part = (float*)sc;                          // [4][32][96] = 49152 B
#pragma unroll
  for (int mt = 0; mt < 2; mt++)
#pragma unroll
    for (int nt = 0; nt < 6; nt++)
#pragma unroll
      for (int t = 0; t < 4; t++)
        part[wid * 3072 + (mt * 16 + lg * 4 + t) * 96 + nt * 16 + lr] = acc2[mt][nt][t];
  __syncthreads();
  for (int idx = tid; idx < 2688; idx += 256) {
    int l = idx / 96, d = idx - (idx / 96) * 96;
    float s = part[idx] + part[3072 + idx] + part[6144 + idx] + part[9216 + idx];
    ctxb[(size_t)(b * 28 + l) * 768 + n * 96 + d] = f2bf(s / rowsum[l]);
  }
}

// ---------------------------------------------------------------------------
__device__ __forceinline__ float blk_sum4(float v, float* red) {
  const int lane = threadIdx.x & 63, wid = threadIdx.x >> 6;
#pragma unroll
  for (int o = 32; o > 0; o >>= 1) v += __shfl_xor(v, o);
  __syncthreads();
  if (lane == 0) red[wid] = v;
  __syncthreads();
  return red[0] + red[1] + red[2] + red[3];
}

__global__ __launch_bounds__(256) void ln1_k(const float* __restrict__ ao, const float* __restrict__ lh,
                                             const float* __restrict__ g, const float* __restrict__ bb,
                                             float* __restrict__ x1, short* __restrict__ x1b) {
  __shared__ float red[4];
  const int row = blockIdx.x, tid = threadIdx.x;
  const size_t base = (size_t)row * 768;
  float x[3], s1 = 0.f, s2 = 0.f;
#pragma unroll
  for (int j = 0; j < 3; j++) {
    int c = tid + j * 256;
    x[j] = ao[base + c] + lh[base + c];
    s1 += x[j]; s2 += x[j] * x[j];
  }
  s1 = blk_sum4(s1, red);
  s2 = blk_sum4(s2, red);
  float mu = s1 * (1.f / 768.f);
  float inv = rsqrtf(s2 * (1.f / 768.f) - mu * mu + 1e-5f);
#pragma unroll
  for (int j = 0; j < 3; j++) {
    int c = tid + j * 256;
    float y = (x[j] - mu) * inv * g[c] + bb[c];
    x1[base + c] = y;
    x1b[base + c] = f2bf(y);
  }
}

__global__ __launch_bounds__(256) void ln2_k(const float* __restrict__ z, const float* __restrict__ x1,
                                             const float* __restrict__ g, const float* __restrict__ bb,
                                             const float* __restrict__ wc, const float* __restrict__ bc,
                                             float* __restrict__ dout) {
  __shared__ float red[4];
  const int row = blockIdx.x, tid = threadIdx.x;
  const size_t base = (size_t)row * 768;
  float x[3], s1 = 0.f, s2 = 0.f;
#pragma unroll
  for (int j = 0; j < 3; j++) {
    int c = tid + j * 256;
    x[j] = z[base + c] + x1[base + c];
    s1 += x[j]; s2 += x[j] * x[j];
  }
  s1 = blk_sum4(s1, red);
  s2 = blk_sum4(s2, red);
  float mu = s1 * (1.f / 768.f);
  float inv = rsqrtf(s2 * (1.f / 768.f) - mu * mu + 1e-5f);
  float dacc = 0.f;
#pragma unroll
  for (int j = 0; j < 3; j++) {
    int c = tid + j * 256;
    float y = (x[j] - mu) * inv * g[c] + bb[c];
    dacc += y * wc[c];
  }
  dacc = blk_sum4(dacc, red);
  if (tid == 0) dout[1 + row] = dacc + bc[0];
}

// merged pair-loss + bce + final loss: one block, 1024 threads.
__global__ __launch_bounds__(1024) void corrloss_k(const float* __restrict__ labels,
                                                   float* __restrict__ dout) {
  __shared__ float lg[896], lb[896];
  __shared__ float red[64];
  const int tid = threadIdx.x;
  if (tid < 896) { lg[tid] = dout[1 + tid]; lb[tid] = labels[tid]; }
  __syncthreads();
  float bce = 0.f, pos = 0.f, neg = 0.f;
  if (tid < 896) {
    float l = lg[tid], y = lb[tid];
    bce = fmaxf(l, 0.f) - l * y + log1pf(expf(-fabsf(l)));
    pos = y; neg = 1.f - y;
  }
  float a = 0.f;
  const int isub = tid >> 5, jsub = tid & 31;
  for (int ib = 0; ib < 28; ib++) {
    int i = ib * 32 + isub;
    if (lb[i] == 1.f) {
      float li = lg[i];
#pragma unroll 4
      for (int jb = 0; jb < 28; jb++) {
        int j = jsub + jb * 32;
        if (lb[j] == 0.f) a += fmaxf(lg[j] - li + 0.3f, 0.f);
      }
    }
  }
#pragma unroll
  for (int o = 32; o > 0; o >>= 1) {
    bce += __shfl_xor(bce, o); pos += __shfl_xor(pos, o);
    neg += __shfl_xor(neg, o); a   += __shfl_xor(a, o);
  }
  const int w = tid >> 6;
  if ((tid & 63) == 0) { red[w] = bce; red[16 + w] = pos; red[32 + w] = neg; red[48 + w] = a; }
  __syncthreads();
  if (tid == 0) {
    float sb = 0.f, sp = 0.f, sn = 0.f, sa = 0.f;
#pragma unroll
    for (int k = 0; k < 16; k++) { sb += red[k]; sp += red[16 + k]; sn += red[32 + k]; sa += red[48 + k]; }
    float denom = sp * sn;
    float corr = denom > 0.f ? sa / fmaxf(denom, 1.f) : 0.f;
    dout[0] = 0.8f * sb * (1.f / 896.f) + 0.2f * corr;
  }
}

// ---------------------------------------------------------------------------
extern "C" void kernel_launch(void* const* d_in, const int* in_sizes, int n_in,
                              void* d_out, int out_size, void* d_ws, size_t ws_size,
                              hipStream_t stream) {
  const float* hidden = (const float*)d_in[0];
  const float* labels = (const float*)d_in[1];
  const int*   lpos   = (const int*)d_in[2];
  const float* Wq = (const float*)d_in[3];  const float* bq = (const float*)d_in[4];
  const float* Wk = (const float*)d_in[5];  const float* bk = (const float*)d_in[6];
  const float* Wv = (const float*)d_in[7];  const float* bv = (const float*)d_in[8];
  const float* Wo = (const float*)d_in[9];  const float* bo = (const float*)d_in[10];
  const float* g_mha = (const float*)d_in[11]; const float* b_mha = (const float*)d_in[12];
  const float* W1 = (const float*)d_in[13]; const float* bf1 = (const float*)d_in[14];
  const float* W2 = (const float*)d_in[15]; const float* bf2 = (const float*)d_in[16];
  const float* g_ffn = (const float*)d_in[17]; const float* b_ffn = (const float*)d_in[18];
  const float* wc = (const float*)d_in[19]; const float* bc = (const float*)d_in[20];
  float* dout = (float*)d_out;

  char* ws = (char*)d_ws;
  size_t off = 0;
  auto alloc = [&](size_t bytes) { char* p = ws + off; off += (bytes + 255) & ~(size_t)255; return p; };
  short* hid_b = (short*)alloc(32ull * 1024 * 768 * 2);
  short* WqT   = (short*)alloc(768ull * 768 * 2);
  short* WkvT  = (short*)alloc(1536ull * 768 * 2);
  short* WoT   = (short*)alloc(768ull * 768 * 2);
  short* W1T   = (short*)alloc(1536ull * 768 * 2);
  short* W2T   = (short*)alloc(768ull * 1536 * 2);
  float* poolf = (float*)alloc(896ull * 768 * 4);
  short* poolb = (short*)alloc(896ull * 768 * 2);
  short* qbf   = (short*)alloc(896ull * 768 * 2);
  short* kbf   = (short*)alloc(32ull * 8 * 1024 * 96 * 2);
  short* vtb   = (short*)alloc(32ull * 8 * 96 * 1024 * 2);
  short* ctxb  = (short*)alloc(896ull * 768 * 2);
  float* aout  = (float*)alloc(896ull * 768 * 4);
  float* x1    = (float*)alloc(896ull * 768 * 4);
  short* x1b   = (short*)alloc(896ull * 768 * 2);
  short* hb    = (short*)alloc(896ull * 1536 * 2);
  float* zbuf  = (float*)alloc(896ull * 768 * 4);
  (void)in_sizes; (void)n_in; (void)out_size; (void)ws_size;

  cvt_k<<<12288, 256, 0, stream>>>(hidden, hid_b);

  TcvtArgs ta;
  ta.src[0] = Wq; ta.dst[0] = WqT;               ta.Kd[0] = 768;  ta.Nd[0] = 768;
  ta.src[1] = Wk; ta.dst[1] = WkvT;              ta.Kd[1] = 768;  ta.Nd[1] = 768;
  ta.src[2] = Wv; ta.dst[2] = WkvT + 768 * 768;  ta.Kd[2] = 768;  ta.Nd[2] = 768;
  ta.src[3] = Wo; ta.dst[3] = WoT;               ta.Kd[3] = 768;  ta.Nd[3] = 768;
  ta.src[4] = W1; ta.dst[4] = W1T;               ta.Kd[4] = 768;  ta.Nd[4] = 1536;
  ta.src[5] = W2; ta.dst[5] = W2T;               ta.Kd[5] = 1536; ta.Nd[5] = 768;
  tcvt_all_k<<<dim3(24, 24, 6), 256, 0, stream>>>(ta);

  pool_k<<<896, 256, 0, stream>>>(hidden, lpos, poolf, poolb);
  // q = label_hidden @ Wq + bq  (84 blocks: 7m x 12n of 128x64)
  gemm_k<0><<<84, 256, 0, stream>>>(poolb, WqT, bq, nullptr, nullptr, qbf, nullptr, 768, 768, 12, 0);
  // k,v = hidden @ [Wk|Wv]  (6144 blocks: 256m x 24n, XCD-swizzled)
  gemm_k<1><<<6144, 256, 0, stream>>>(hid_b, WkvT, bk, bv, nullptr, kbf, vtb, 768, 1536, 24, 1);
  attn_k<<<256, 256, 0, stream>>>(qbf, kbf, vtb, ctxb);
  // attn_out = ctx @ Wo + bo
  gemm_k<2><<<84, 256, 0, stream>>>(ctxb, WoT, bo, nullptr, aout, nullptr, nullptr, 768, 768, 12, 0);
  ln1_k<<<896, 256, 0, stream>>>(aout, poolf, g_mha, b_mha, x1, x1b);
  // h = gelu(x1 @ W1 + bf1)  (168 blocks: 7m x 24n)
  gemm_k<3><<<168, 256, 0, stream>>>(x1b, W1T, bf1, nullptr, nullptr, hb, nullptr, 768, 1536, 24, 0);
  // z = h @ W2 + bf2  (84 blocks, K=1536)
  gemm_k<2><<<84, 256, 0, stream>>>(hb, W2T, bf2, nullptr, zbuf, nullptr, nullptr, 1536, 768, 12, 0);
  ln2_k<<<896, 256, 0, stream>>>(zbuf, x1, g_ffn, b_ffn, wc, bc, dout);
  corrloss_k<<<1, 1024, 0, stream>>>(labels, dout);
}